// Round 6
// baseline (410.840 us; speedup 1.0000x reference)
//
#include <hip/hip_runtime.h>

#define EPSV 1e-5f

typedef short bf16x8 __attribute__((ext_vector_type(8)));
typedef float f32x4 __attribute__((ext_vector_type(4)));

#define NBLK 512

static __device__ __forceinline__ unsigned short f2b(float f) {
  union { float f; unsigned u; } v; v.f = f;
  return (unsigned short)((v.u + 0x7fffu + ((v.u >> 16) & 1u)) >> 16);
}

// Grid barrier without cooperative launch. All NBLK blocks are co-resident by
// construction (512 blocks = 2/CU x 256 CU; launch_bounds + 17.4KB LDS allow it).
// Each sync point uses its OWN counter (zeroed host-side): arrive with
// acq_rel agent-scope RMW (publishes this block's writes), spin-acquire until
// all arrived (invalidates stale caches). Spin is bounded: a co-residency
// failure produces a wrong answer, never a hang.
static __device__ __forceinline__ void gbar(int* bar) {
  __syncthreads();
  if (threadIdx.x == 0) {
    __hip_atomic_fetch_add(bar, 1, __ATOMIC_ACQ_REL, __HIP_MEMORY_SCOPE_AGENT);
    for (int it = 0; it < (1 << 27); ++it) {
      if (__hip_atomic_load(bar, __ATOMIC_ACQUIRE, __HIP_MEMORY_SCOPE_AGENT) >= NBLK)
        break;
    }
  }
  __syncthreads();
}

// One kernel, 512 blocks x 256 threads (2 blocks/CU co-resident).
//  P1: zero out + Wfc->bf16 swizzle (all blocks) + x col partial stats (blk<256)
//  P2: reduce partials + BN1 finalize -> pt rows 0..15   (blk<32)
//  P3: batch stats of layer-2 preact, 1024 tiles, 2/block (all blocks)
//  P4: reduce + BN2 finalize -> pt rows 16..51           (blk<16)
//  P5: fused A-gen + bf16 MFMA GEMM, K-split=4, atomic merge
// pt layout [param i][d]: 0..7=s1_i, 8..15=t1_i, 16..47=W2s(o*8+i), 48..51=t2c
// wb frag layout: frag=k32b*16+nb; lane(quad,l15): n=nb*16+l15, k=k32b*32+quad*8
__global__ __launch_bounds__(256, 2) void k_all(
    const float* __restrict__ x, const float* __restrict__ W1,
    const float* __restrict__ g1, const float* __restrict__ be1,
    const float* __restrict__ W2, const float* __restrict__ g2,
    const float* __restrict__ be2, const float* __restrict__ wfc,
    const float* __restrict__ bfc, unsigned short* __restrict__ wb,
    float* __restrict__ pt, float* __restrict__ ps1,
    float* __restrict__ ps2s, float* __restrict__ ps2q,
    int* __restrict__ bars, float* __restrict__ out) {
  __shared__ __align__(16) unsigned char smem[64 * 136 * 2];  // 17408 B union
  const int t = threadIdx.x;
  const int blk = blockIdx.x;

  // ---------------- P1 ----------------
  {
    // zero the output (atomic-merge target in P5)
    const size_t gid = (size_t)blk * 256 + t;
    float4 z4 = {0.f, 0.f, 0.f, 0.f};
    float4* ob = (float4*)(out + gid * 16);
#pragma unroll
    for (int j = 0; j < 4; ++j) ob[j] = z4;

    // Wfc -> bf16 swizzled fragments (all 512 blocks)
    const int f = blk * 256 + t;                         // 0..131071
    const int l15 = f & 15, quad = (f >> 4) & 3, nb = (f >> 6) & 15, k32b = f >> 10;
    const int n = nb * 16 + l15;
    const int k = k32b * 32 + quad * 8;
    const float4* src = (const float4*)(wfc + (size_t)n * 4096 + k);
    float4 a = src[0], b = src[1];
    ushort4 o0, o1;
    o0.x = f2b(a.x); o0.y = f2b(a.y); o0.z = f2b(a.z); o0.w = f2b(a.w);
    o1.x = f2b(b.x); o1.y = f2b(b.y); o1.z = f2b(b.z); o1.w = f2b(b.w);
    *(ushort4*)(wb + (size_t)f * 8) = o0;
    *(ushort4*)(wb + (size_t)f * 8 + 4) = o1;

    // x column partial stats: blocks 0..255, 32 rows each
    if (blk < 256) {
      const int c = t * 4;
      const int r0 = blk * 32;
      float4 s = {0.f,0.f,0.f,0.f}, q = {0.f,0.f,0.f,0.f};
      for (int g = 0; g < 4; ++g) {
        float4 v[8];
#pragma unroll
        for (int j = 0; j < 8; ++j)
          v[j] = *(const float4*)(x + (size_t)(r0 + g*8 + j) * 1024 + c);
#pragma unroll
        for (int j = 0; j < 8; ++j) {
          s.x += v[j].x; s.y += v[j].y; s.z += v[j].z; s.w += v[j].w;
          q.x = fmaf(v[j].x, v[j].x, q.x); q.y = fmaf(v[j].y, v[j].y, q.y);
          q.z = fmaf(v[j].z, v[j].z, q.z); q.w = fmaf(v[j].w, v[j].w, q.w);
        }
      }
      *(float4*)(ps1 + (size_t)blk * 2048 + c) = s;
      *(float4*)(ps1 + (size_t)blk * 2048 + 1024 + c) = q;
    }
  }
  gbar(&bars[0]);

  // ---------------- P2: BN1 finalize ----------------
  if (blk < 32) {
    float (*redS)[32] = (float (*)[32])smem;
    float (*redQ)[32] = (float (*)[32])(smem + 8 * 32 * 4);
    const int d0 = blk * 32;
    const int dl = t & 31, slot = t >> 5;
    float s = 0.f, q = 0.f;
    for (int u = 0; u < 32; u += 8) {
#pragma unroll
      for (int w = 0; w < 8; ++w) {
        const size_t base = (size_t)(slot * 32 + u + w) * 2048 + d0 + dl;
        s += ps1[base];
        q += ps1[base + 1024];
      }
    }
    redS[slot][dl] = s; redQ[slot][dl] = q;
    __syncthreads();
    const int dloc = t >> 3, i = t & 7;
    float xs = 0.f, xq = 0.f;
#pragma unroll
    for (int p = 0; p < 8; ++p) { xs += redS[p][dloc]; xq += redQ[p][dloc]; }
    const float inv = 1.f / 8192.f;
    const int d = d0 + dloc;
    const int c = d * 8 + i;
    float mean = xs * inv;
    float var = xq * inv - mean * mean;
    float w = W1[c];
    float s1 = g1[c] * w * rsqrtf(w * w * var + EPSV);
    float t1 = be1[c] - s1 * mean;
    pt[i * 1024 + d] = s1;
    pt[(8 + i) * 1024 + d] = t1;
  }
  gbar(&bars[1]);

  // ---------------- P3: layer-2 preact batch stats (2 tiles/block) ----------
  {
    float (*red)[32][8] = (float (*)[32][8])smem;
    const int dl = t & 31, slot = t >> 5;
#pragma unroll
    for (int it = 0; it < 2; ++it) {
      const int tile = blk * 2 + it;                     // 0..1023
      const int dgrp = tile & 31, bgrp = tile >> 5;
      const int d = dgrp * 32 + dl;
      float s1v[8], t1v[8], w2v[32];
#pragma unroll
      for (int i = 0; i < 8; ++i) s1v[i] = pt[i * 1024 + d];
#pragma unroll
      for (int i = 0; i < 8; ++i) t1v[i] = pt[(8 + i) * 1024 + d];
      const float4* wp = (const float4*)(W2 + (size_t)d * 32);
#pragma unroll
      for (int i = 0; i < 8; ++i) {
        float4 v = wp[i];
        w2v[i*4+0]=v.x; w2v[i*4+1]=v.y; w2v[i*4+2]=v.z; w2v[i*4+3]=v.w;
      }
      float s[4] = {0.f,0.f,0.f,0.f}, q[4] = {0.f,0.f,0.f,0.f};
      const int b0 = bgrp * 256 + slot * 32;
      for (int r = 0; r < 32; r += 8) {
        float xv[8];
#pragma unroll
        for (int j = 0; j < 8; ++j)
          xv[j] = x[(size_t)(b0 + r + j) * 1024 + d];
#pragma unroll
        for (int j = 0; j < 8; ++j) {
          float a1[8];
#pragma unroll
          for (int i = 0; i < 8; ++i) a1[i] = fmaxf(fmaf(s1v[i], xv[j], t1v[i]), 0.f);
#pragma unroll
          for (int o = 0; o < 4; ++o) {
            float h = 0.f;
#pragma unroll
            for (int i = 0; i < 8; ++i) h = fmaf(a1[i], w2v[o*8+i], h);
            s[o] += h;
            q[o] = fmaf(h, h, q[o]);
          }
        }
      }
      __syncthreads();   // WAR: previous iteration's readers done with smem
#pragma unroll
      for (int j = 0; j < 4; ++j) {
        red[slot][dl][j] = s[j];
        red[slot][dl][4+j] = q[j];
      }
      __syncthreads();
      const int d2l = t >> 3, j = t & 7;
      float v = 0.f;
#pragma unroll
      for (int p = 0; p < 8; ++p) v += red[p][d2l][j];
      const int c2 = (dgrp * 32 + d2l) * 4 + (t & 3);
      if (j < 4) ps2s[(size_t)bgrp * 4096 + c2] = v;
      else       ps2q[(size_t)bgrp * 4096 + c2] = v;
    }
  }
  gbar(&bars[2]);

  // ---------------- P4: BN2 finalize ----------------
  if (blk < 16) {
    const int c2 = blk * 256 + t;                        // 0..4095
    const int d = c2 >> 2, o = c2 & 3;
    float sm = 0.f, sq = 0.f;
#pragma unroll
    for (int b = 0; b < 32; ++b) {
      sm += ps2s[(size_t)b * 4096 + c2];
      sq += ps2q[(size_t)b * 4096 + c2];
    }
    const float inv = 1.f / 8192.f;
    float m = sm * inv;
    float var = sq * inv - m * m;
    float s2 = g2[c2] * rsqrtf(var + EPSV);
    float t2 = be2[c2] - s2 * m;
    pt[(48 + o) * 1024 + d] = t2;
#pragma unroll
    for (int i = 0; i < 8; ++i)
      pt[(16 + o * 8 + i) * 1024 + d] = W2[(size_t)d * 32 + o * 8 + i] * s2;
  }
  gbar(&bars[3]);

  // ---------------- P5: fused A-gen + GEMM ----------------
  {
    // stride 136 shorts = 68 dwords (== 4 mod 32): b128 reads tile banks evenly
    unsigned short* As = (unsigned short*)smem;
    const int lane = t & 63;
    const int wv = t >> 6;
    const int mt0 = blk & 127;
    const int kQ = blk >> 7;
    const int m0 = mt0 * 64;
    const int d0 = kQ * 256;
    const int quad = lane >> 4;
    const int l15 = lane & 15;
    const int dl = t & 31, bs = t >> 5;
    const int chrot = (mt0 & 1) << 2;

    f32x4 acc[4][4];
#pragma unroll
    for (int mt = 0; mt < 4; ++mt)
#pragma unroll
      for (int nt = 0; nt < 4; ++nt) {
        f32x4 z = {0.f, 0.f, 0.f, 0.f};
        acc[mt][nt] = z;
      }

    for (int chi = 0; chi < 8; ++chi) {
      const int ch = (chi + chrot) & 7;
      const int d = d0 + ch * 32 + dl;
      float pv[52];
#pragma unroll
      for (int i = 0; i < 52; ++i) pv[i] = pt[i * 1024 + d];
      __syncthreads();   // previous MFMA phase done reading As
#pragma unroll
      for (int r = 0; r < 8; ++r) {
        const int bl = bs * 8 + r;
        float xv = x[(size_t)(m0 + bl) * 1024 + d];
        float a1[8];
#pragma unroll
        for (int i = 0; i < 8; ++i) a1[i] = fmaxf(fmaf(pv[i], xv, pv[8+i]), 0.f);
        unsigned short o4[4];
#pragma unroll
        for (int o = 0; o < 4; ++o) {
          float h = pv[48 + o];
#pragma unroll
          for (int i = 0; i < 8; ++i) h = fmaf(a1[i], pv[16 + o*8 + i], h);
          o4[o] = f2b(fmaxf(h, 0.f));
        }
        *(ushort4*)&As[bl * 136 + dl * 4] = make_ushort4(o4[0], o4[1], o4[2], o4[3]);
      }
      __syncthreads();
#pragma unroll
      for (int kk = 0; kk < 4; ++kk) {
        bf16x8 af[4];
#pragma unroll
        for (int mt = 0; mt < 4; ++mt)
          af[mt] = *(const bf16x8*)&As[(mt*16 + l15) * 136 + kk*32 + quad*8];
        const int k32b = kQ * 32 + ch * 4 + kk;
#pragma unroll
        for (int nt = 0; nt < 4; ++nt) {
          const int frag = k32b * 16 + wv * 4 + nt;
          bf16x8 bfr = *(const bf16x8*)&wb[((size_t)frag * 64 + lane) * 8];
#pragma unroll
          for (int mt = 0; mt < 4; ++mt)
            acc[mt][nt] = __builtin_amdgcn_mfma_f32_16x16x32_bf16(af[mt], bfr,
                                                                  acc[mt][nt], 0, 0, 0);
        }
      }
    }
#pragma unroll
    for (int nt = 0; nt < 4; ++nt) {
      const int col = wv * 64 + nt * 16 + l15;
      const float bias = (kQ == 0) ? bfc[col] : 0.f;
#pragma unroll
      for (int mt = 0; mt < 4; ++mt) {
#pragma unroll
        for (int r = 0; r < 4; ++r) {
          const int row = m0 + mt * 16 + quad * 4 + r;
          atomicAdd(&out[(size_t)row * 256 + col], acc[mt][nt][r] + bias);
        }
      }
    }
  }
}

extern "C" void kernel_launch(void* const* d_in, const int* in_sizes, int n_in,
                              void* d_out, int out_size, void* d_ws, size_t ws_size,
                              hipStream_t stream) {
  const float* x   = (const float*)d_in[0];
  const float* W1  = (const float*)d_in[1];
  // d_in[2]=b1, d_in[6]=b2 cancel inside the train-mode batchnorms
  const float* g1  = (const float*)d_in[3];
  const float* be1 = (const float*)d_in[4];
  const float* W2  = (const float*)d_in[5];
  const float* g2  = (const float*)d_in[7];
  const float* be2 = (const float*)d_in[8];
  const float* Wfc = (const float*)d_in[9];
  const float* bfc = (const float*)d_in[10];
  float* out = (float*)d_out;

  char* ws = (char*)d_ws;
  unsigned short* wb = (unsigned short*)ws;                  // 2 MB swizzled bf16 Wfc
  float* pt   = (float*)(ws + (2u << 20));                   // 256 KB [param][d]
  float* ps1  = (float*)(ws + (2u << 20) + (256u << 10));    // 2 MB stats1 partials
  float* ps2s = ps1;                                         // reuse after P2
  float* ps2q = ps1 + (512u << 10) / 4;                      // +512 KB
  int*   bars = (int*)(ws + (4u << 20) + (256u << 10));      // 16 B counters

  hipMemsetAsync(bars, 0, 4 * sizeof(int), stream);

  k_all<<<dim3(NBLK), dim3(256), 0, stream>>>(
      x, W1, g1, be1, W2, g2, be2, Wfc, bfc,
      wb, pt, ps1, ps2s, ps2q, bars, out);
}

// Round 7
// 227.187 us; speedup vs baseline: 1.8084x; 1.8084x over previous
//
#include <hip/hip_runtime.h>

#define EPSV 1e-5f

typedef short bf16x8 __attribute__((ext_vector_type(8)));
typedef float f32x4 __attribute__((ext_vector_type(4)));

static __device__ __forceinline__ unsigned short f2b(float f) {
  union { float f; unsigned u; } v; v.f = f;
  return (unsigned short)((v.u + 0x7fffu + ((v.u >> 16) & 1u)) >> 16);
}

// ---------- kernel 1: out-zero + Wfc->bf16 swizzle (blk<512) +
//                      x column partial stats (blk 512..767) ----------
// wb frag layout: frag=k32b*16+nb; lane(quad,l15): n=nb*16+l15, k=k32b*32+quad*8
// ps1[blk][0:1024)=colsum, [1024:2048)=colsumsq  (256 partial blocks)
__global__ __launch_bounds__(256) void k_pre(const float* __restrict__ wfc,
    unsigned short* __restrict__ wb, const float* __restrict__ x,
    float* __restrict__ ps1, float* __restrict__ out) {
  const int t = threadIdx.x;
  if (blockIdx.x < 512) {
    const int blk = blockIdx.x;
    // zero the output (atomic-merge target of k_gemm, two kernels later)
    const size_t gid = (size_t)blk * 256 + t;
    float4 z4 = {0.f, 0.f, 0.f, 0.f};
    float4* ob = (float4*)(out + gid * 16);
#pragma unroll
    for (int j = 0; j < 4; ++j) ob[j] = z4;
    // Wfc -> bf16 swizzled fragments
    const int f = blk * 256 + t;                         // 0..131071
    const int l15 = f & 15, quad = (f >> 4) & 3, nb = (f >> 6) & 15, k32b = f >> 10;
    const int n = nb * 16 + l15;
    const int k = k32b * 32 + quad * 8;
    const float4* src = (const float4*)(wfc + (size_t)n * 4096 + k);
    float4 a = src[0], b = src[1];
    ushort4 o0, o1;
    o0.x = f2b(a.x); o0.y = f2b(a.y); o0.z = f2b(a.z); o0.w = f2b(a.w);
    o1.x = f2b(b.x); o1.y = f2b(b.y); o1.z = f2b(b.z); o1.w = f2b(b.w);
    *(ushort4*)(wb + (size_t)f * 8) = o0;
    *(ushort4*)(wb + (size_t)f * 8 + 4) = o1;
  } else {
    const int blk = blockIdx.x - 512;                    // 0..255
    const int c = t * 4;
    const int r0 = blk * 32;
    float4 s = {0.f,0.f,0.f,0.f}, q = {0.f,0.f,0.f,0.f};
    for (int g = 0; g < 4; ++g) {
      float4 v[8];
#pragma unroll
      for (int j = 0; j < 8; ++j)
        v[j] = *(const float4*)(x + (size_t)(r0 + g*8 + j) * 1024 + c);
#pragma unroll
      for (int j = 0; j < 8; ++j) {
        s.x += v[j].x; s.y += v[j].y; s.z += v[j].z; s.w += v[j].w;
        q.x = fmaf(v[j].x, v[j].x, q.x); q.y = fmaf(v[j].y, v[j].y, q.y);
        q.z = fmaf(v[j].z, v[j].z, q.z); q.w = fmaf(v[j].w, v[j].w, q.w);
      }
    }
    *(float4*)(ps1 + (size_t)blk * 2048 + c) = s;
    *(float4*)(ps1 + (size_t)blk * 2048 + 1024 + c) = q;
  }
}

// ---------- kernel 2: per-block BN1 finalize + layer-2 preact batch stats ----
// grid (32 dgrp, 32 bgrp). Each block re-reduces ps1 for its 32 d (redundant
// across bgrp — cheaper than a separate kernel launch). bgrp==0 publishes
// s1/t1 to pt rows 0..15 for k_gemm's A-gen.
__global__ __launch_bounds__(256) void k_stats2(const float* __restrict__ x,
    const float* __restrict__ ps1, const float* __restrict__ W1,
    const float* __restrict__ g1, const float* __restrict__ be1,
    const float* __restrict__ W2, float* __restrict__ pt,
    float* __restrict__ ps2s, float* __restrict__ ps2q) {
  __shared__ float rs[8][32], rq[8][32];
  __shared__ float red[8][32][8];
  const int t = threadIdx.x;
  const int dl = t & 31, slot = t >> 5;
  const int d = blockIdx.x * 32 + dl;
  // xstats reduce: slot-strided over the 256 partial blocks
  {
    float s = 0.f, q = 0.f;
    for (int u = 0; u < 32; u += 4) {
#pragma unroll
      for (int w = 0; w < 4; ++w) {
        const size_t base = (size_t)(slot + (u + w) * 8) * 2048 + d;
        s += ps1[base];
        q += ps1[base + 1024];
      }
    }
    rs[slot][dl] = s; rq[slot][dl] = q;
  }
  __syncthreads();
  float xs = 0.f, xq = 0.f;
#pragma unroll
  for (int p = 0; p < 8; ++p) { xs += rs[p][dl]; xq += rq[p][dl]; }
  const float inv = 1.f / 8192.f;
  const float mean = xs * inv;
  const float var = xq * inv - mean * mean;
  float s1v[8], t1v[8], w2v[32];
#pragma unroll
  for (int i = 0; i < 8; ++i) {
    const int c = d * 8 + i;
    float w = W1[c];
    s1v[i] = g1[c] * w * rsqrtf(w * w * var + EPSV);
    t1v[i] = be1[c] - s1v[i] * mean;
  }
  if (blockIdx.y == 0 && slot == 0) {
#pragma unroll
    for (int i = 0; i < 8; ++i) {
      pt[i * 1024 + d] = s1v[i];
      pt[(8 + i) * 1024 + d] = t1v[i];
    }
  }
  const float4* wp = (const float4*)(W2 + (size_t)d * 32);
#pragma unroll
  for (int i = 0; i < 8; ++i) {
    float4 v = wp[i];
    w2v[i*4+0]=v.x; w2v[i*4+1]=v.y; w2v[i*4+2]=v.z; w2v[i*4+3]=v.w;
  }
  float s[4] = {0.f,0.f,0.f,0.f}, q[4] = {0.f,0.f,0.f,0.f};
  const int b0 = blockIdx.y * 256 + slot * 32;
  for (int r = 0; r < 32; r += 8) {
    float xv[8];
#pragma unroll
    for (int j = 0; j < 8; ++j)
      xv[j] = x[(size_t)(b0 + r + j) * 1024 + d];
#pragma unroll
    for (int j = 0; j < 8; ++j) {
      float a1[8];
#pragma unroll
      for (int i = 0; i < 8; ++i) a1[i] = fmaxf(fmaf(s1v[i], xv[j], t1v[i]), 0.f);
#pragma unroll
      for (int o = 0; o < 4; ++o) {
        float h = 0.f;
#pragma unroll
        for (int i = 0; i < 8; ++i) h = fmaf(a1[i], w2v[o*8+i], h);
        s[o] += h;
        q[o] = fmaf(h, h, q[o]);
      }
    }
  }
#pragma unroll
  for (int j = 0; j < 4; ++j) {
    red[slot][dl][j] = s[j];
    red[slot][dl][4+j] = q[j];
  }
  __syncthreads();
  const int d2l = t >> 3, j = t & 7;
  float v = 0.f;
#pragma unroll
  for (int p = 0; p < 8; ++p) v += red[p][d2l][j];
  const int c2 = (blockIdx.x * 32 + d2l) * 4 + (t & 3);
  if (j < 4) ps2s[(size_t)blockIdx.y * 4096 + c2] = v;
  else       ps2q[(size_t)blockIdx.y * 4096 + c2] = v;
}

// ---------- kernel 3: per-block BN2 finalize + fused A-gen + GEMM ----------
// BM=64, BN=256, chunk=32 d, K-split=8; grid (128,8) x 256 -> 4 blocks/CU.
// Each block reduces ps2 for its 128 d into an LDS table (stride 37:
// conflict-free scalar reads), then runs the A-gen/MFMA loop.
__global__ __launch_bounds__(256, 4) void k_gemm(const float* __restrict__ x,
    const float* __restrict__ pt, const unsigned short* __restrict__ wb,
    const float* __restrict__ W2, const float* __restrict__ g2,
    const float* __restrict__ be2, const float* __restrict__ ps2s,
    const float* __restrict__ ps2q, const float* __restrict__ bfc,
    float* __restrict__ out) {
  // As stride 136 shorts = 68 dwords (== 4 mod 32): b128 reads tile banks evenly
  __shared__ __align__(16) unsigned short As[64 * 136];   // 17408 B
  __shared__ float prm[128 * 37];                         // 18944 B
  const int t = threadIdx.x;
  const int lane = t & 63;
  const int wv = t >> 6;
  const int mt0 = blockIdx.x;
  const int kQ = blockIdx.y;                              // 0..7
  const int m0 = mt0 * 64;
  const int quad = lane >> 4;
  const int l15 = lane & 15;
  const int dl = t & 31, bs = t >> 5;
  const int chrot = mt0 & 3;

  // ---- build phase: BN2 finalize for this block's 512 c2 ----
#pragma unroll
  for (int rr = 0; rr < 2; ++rr) {
    const int c2l = rr * 256 + t;                         // 0..511
    const int c2 = kQ * 512 + c2l;
    float sm = 0.f, sq = 0.f;
#pragma unroll
    for (int p = 0; p < 32; ++p) {
      sm += ps2s[(size_t)p * 4096 + c2];
      sq += ps2q[(size_t)p * 4096 + c2];
    }
    const float inv = 1.f / 8192.f;
    float m = sm * inv;
    float var = sq * inv - m * m;
    float s2 = g2[c2] * rsqrtf(var + EPSV);
    float t2 = be2[c2] - s2 * m;
    const int dloc = c2l >> 2, o = c2l & 3;
    prm[dloc * 37 + 32 + o] = t2;
#pragma unroll
    for (int i = 0; i < 8; ++i)
      prm[dloc * 37 + o * 8 + i] =
          W2[(size_t)(kQ * 128 + dloc) * 32 + o * 8 + i] * s2;
  }
  __syncthreads();

  f32x4 acc[4][4];
#pragma unroll
  for (int mt = 0; mt < 4; ++mt)
#pragma unroll
    for (int nt = 0; nt < 4; ++nt) {
      f32x4 z = {0.f, 0.f, 0.f, 0.f};
      acc[mt][nt] = z;
    }

  for (int chi = 0; chi < 4; ++chi) {
    const int ch = (chi + chrot) & 3;
    const int dloc0 = ch * 32 + dl;
    const int d = kQ * 128 + dloc0;
    float pv[16], w2s[32], t2c[4];
#pragma unroll
    for (int i = 0; i < 16; ++i) pv[i] = pt[i * 1024 + d];
#pragma unroll
    for (int j = 0; j < 32; ++j) w2s[j] = prm[dloc0 * 37 + j];
#pragma unroll
    for (int o = 0; o < 4; ++o) t2c[o] = prm[dloc0 * 37 + 32 + o];
    __syncthreads();   // previous MFMA phase done reading As
    // ---- A-gen: 64 b x 32 d x 4 o2 tile in bf16 ----
#pragma unroll
    for (int r = 0; r < 8; ++r) {
      const int bl = bs * 8 + r;
      float xv = x[(size_t)(m0 + bl) * 1024 + d];
      float a1[8];
#pragma unroll
      for (int i = 0; i < 8; ++i) a1[i] = fmaxf(fmaf(pv[i], xv, pv[8+i]), 0.f);
      unsigned short o4[4];
#pragma unroll
      for (int o = 0; o < 4; ++o) {
        float h = t2c[o];
#pragma unroll
        for (int i = 0; i < 8; ++i) h = fmaf(a1[i], w2s[o*8+i], h);
        o4[o] = f2b(fmaxf(h, 0.f));
      }
      *(ushort4*)&As[bl * 136 + dl * 4] = make_ushort4(o4[0], o4[1], o4[2], o4[3]);
    }
    __syncthreads();
    // ---- MFMA phase; B loads are contiguous 1KB wave-loads ----
#pragma unroll
    for (int kk = 0; kk < 4; ++kk) {
      bf16x8 af[4];
#pragma unroll
      for (int mt = 0; mt < 4; ++mt)
        af[mt] = *(const bf16x8*)&As[(mt*16 + l15) * 136 + kk*32 + quad*8];
      const int k32b = kQ * 16 + ch * 4 + kk;
#pragma unroll
      for (int nt = 0; nt < 4; ++nt) {
        const int frag = k32b * 16 + wv * 4 + nt;
        bf16x8 bfr = *(const bf16x8*)&wb[((size_t)frag * 64 + lane) * 8];
#pragma unroll
        for (int mt = 0; mt < 4; ++mt)
          acc[mt][nt] = __builtin_amdgcn_mfma_f32_16x16x32_bf16(af[mt], bfr,
                                                                acc[mt][nt], 0, 0, 0);
      }
    }
  }
  // ---- epilogue: atomic merge of 8 K-splits; split 0 adds bias ----
#pragma unroll
  for (int nt = 0; nt < 4; ++nt) {
    const int col = wv * 64 + nt * 16 + l15;
    const float bias = (kQ == 0) ? bfc[col] : 0.f;
#pragma unroll
    for (int mt = 0; mt < 4; ++mt) {
#pragma unroll
      for (int r = 0; r < 4; ++r) {
        const int row = m0 + mt * 16 + quad * 4 + r;
        atomicAdd(&out[(size_t)row * 256 + col], acc[mt][nt][r] + bias);
      }
    }
  }
}

extern "C" void kernel_launch(void* const* d_in, const int* in_sizes, int n_in,
                              void* d_out, int out_size, void* d_ws, size_t ws_size,
                              hipStream_t stream) {
  const float* x   = (const float*)d_in[0];
  const float* W1  = (const float*)d_in[1];
  // d_in[2]=b1, d_in[6]=b2 cancel inside the train-mode batchnorms
  const float* g1  = (const float*)d_in[3];
  const float* be1 = (const float*)d_in[4];
  const float* W2  = (const float*)d_in[5];
  const float* g2  = (const float*)d_in[7];
  const float* be2 = (const float*)d_in[8];
  const float* Wfc = (const float*)d_in[9];
  const float* bfc = (const float*)d_in[10];
  float* out = (float*)d_out;

  char* ws = (char*)d_ws;
  unsigned short* wb = (unsigned short*)ws;                  // 2 MB swizzled bf16 Wfc
  float* pt   = (float*)(ws + (2u << 20));                   // 64 KB s1/t1 [i][d]
  float* ps1  = (float*)(ws + (2u << 20) + (256u << 10));    // 2 MB stats1 partials
  float* ps2s = (float*)(ws + (4u << 20) + (256u << 10));    // 512 KB stats2 sum
  float* ps2q = (float*)(ws + (4u << 20) + (768u << 10));    // 512 KB stats2 sq

  k_pre   <<<dim3(768),    256, 0, stream>>>(Wfc, wb, x, ps1, out);
  k_stats2<<<dim3(32, 32), 256, 0, stream>>>(x, ps1, W1, g1, be1, W2, pt, ps2s, ps2q);
  k_gemm  <<<dim3(128, 8), 256, 0, stream>>>(x, pt, wb, W2, g2, be2, ps2s, ps2q,
                                             bfc, out);
}